// Round 2
// baseline (1422.183 us; speedup 1.0000x reference)
//
#include <hip/hip_runtime.h>

__device__ __forceinline__ float sigf(float v) {
    return 1.0f / (1.0f + __expf(-v));
}
__device__ __forceinline__ float tanh_fast(float v) {
    return 1.0f - 2.0f / (__expf(2.0f * v) + 1.0f);
}

// sigd4[i] = 0.25 * sigmoid(decays[i]), i < 2048  (batch-independent)
__global__ void organism_prep(const float* __restrict__ decays,
                              float* __restrict__ sigd4) {
    const int i = blockIdx.x * 256 + threadIdx.x;
    if (i < 2048) sigd4[i] = 0.25f * sigf(decays[i]);
}

// One 64-thread block per 64 rows. H tiles [64 rows x 64 floats] are loaded
// coalesced (4 contiguous 256B segments per wave instruction), staged through
// padded LDS (stride 68 floats = 272B, 16B aligned), then consumed per-row.
// Single wave per block -> DS in-order, no barriers needed.
__global__ __launch_bounds__(64)
void organism_main(const float* __restrict__ x,
                   const float* __restrict__ H,
                   const float* __restrict__ W_bit,
                   const float* __restrict__ b_bit,
                   const float* __restrict__ W_bridge,
                   const float* __restrict__ W_read,
                   const float* __restrict__ b_read,
                   const float* __restrict__ W_sh,
                   const float* __restrict__ b_sh,
                   const float* __restrict__ W_eng,
                   const float* __restrict__ b_eng,
                   const float* __restrict__ W_imp,
                   const float* __restrict__ b_imp,
                   const float* __restrict__ W_sur,
                   const float* __restrict__ b_sur,
                   const float* __restrict__ W_gate,
                   const float* __restrict__ b_gate,
                   const float* __restrict__ halt_w,
                   const float* __restrict__ halt_b,
                   const float* __restrict__ sigd4,
                   float* __restrict__ out)
{
    const int t   = threadIdx.x;
    const int row = blockIdx.x * 64 + t;
    const int lr  = t >> 4;      // 0..3  : row-group within a load step
    const int lj  = t & 15;      // 0..15 : float4 column within 256B segment

    __shared__ float tile[2][64 * 68];   // 34,816 B

    const float* __restrict__ Hblk = H + (size_t)blockIdx.x * 64 * 2048;

    // ---- prefetch tile (c=0, l=0) while phase A computes ----
    float4 pf[16];
#pragma unroll
    for (int i = 0; i < 16; ++i)
        pf[i] = *(const float4*)(Hblk + (size_t)(4 * i + lr) * 2048 + lj * 4);

    // ================= phase A: small network (term2) =================
    float xv[8];
    {
        const float4 x0 = *(const float4*)(x + (size_t)row * 8);
        const float4 x1 = *(const float4*)(x + (size_t)row * 8 + 4);
        xv[0]=x0.x; xv[1]=x0.y; xv[2]=x0.z; xv[3]=x0.w;
        xv[4]=x1.x; xv[5]=x1.y; xv[6]=x1.z; xv[7]=x1.w;
    }

    float s1[32];
#pragma unroll
    for (int i = 0; i < 32; ++i) {
        float a = b_bit[i];
#pragma unroll
        for (int k = 0; k < 8; ++k) a += W_bit[i*8+k] * xv[k];
        s1[i] = a;
    }

    float sa = b_sur[0], ga = b_gate[0];
#pragma unroll
    for (int i = 0; i < 32; ++i) {
        sa += W_sur[i]  * s1[i];
        ga += W_gate[i] * s1[i];
    }
    const float sur = sigf(sa) * sigf(ga);

    float s2[64];
#pragma unroll
    for (int m = 0; m < 64; ++m) {
        float a = 0.0f;
#pragma unroll
        for (int i = 0; i < 32; ++i) a += W_bridge[m*32+i] * s1[i];
        s2[m] = tanh_fast(a);
    }

    float ea = b_eng[0], ia = b_imp[0];
    for (int n = 0; n < 64; ++n) {
        float a = b_sh[n];
#pragma unroll
        for (int m = 0; m < 64; ++m) a += W_sh[n*64+m] * s2[m];
        a = fmaxf(a, 0.0f);
        ea += W_eng[n] * a;
        ia += W_imp[n] * a;
    }
    const float ei = sigf(ea) * sigf(ia);

    float wv[64];
#pragma unroll
    for (int m = 0; m < 64; ++m) wv[m] = sur * s2[m];

    float out2[8] = {0,0,0,0,0,0,0,0};
    for (int r = 0; r < 8; ++r) {
        float hs = 0.0f;
#pragma unroll
        for (int l = 0; l < 4; ++l) {
            float a = halt_b[l];
#pragma unroll
            for (int m = 0; m < 64; ++m) a += halt_w[(l*8+r)*64+m] * s2[m];
            hs += sigf(a);
        }
        const float gr = 0.25f * ei * hs;
#pragma unroll
        for (int o = 0; o < 8; ++o) {
            float p = 0.0f;
#pragma unroll
            for (int m = 0; m < 64; ++m) p += W_read[o*512 + r*64 + m] * wv[m];
            out2[o] += gr * p;
        }
    }

    // ================= phase B: stream H (term1) =================
    float acc[8] = {0,0,0,0,0,0,0,0};
    float g[64];
    int buf = 0;

    auto store_tile = [&](int b) {
#pragma unroll
        for (int i = 0; i < 16; ++i)
            *(float4*)(&tile[b][(4 * i + lr) * 68 + lj * 4]) = pf[i];
    };
    auto prefetch = [&](int c, int l) {
#pragma unroll
        for (int i = 0; i < 16; ++i)
            pf[i] = *(const float4*)(Hblk + (size_t)(4 * i + lr) * 2048
                                     + l * 512 + c * 64 + lj * 4);
    };

#pragma unroll 1
    for (int c = 0; c < 8; ++c) {
#pragma unroll
        for (int l = 0; l < 4; ++l) {
            store_tile(buf);
            if (l < 3)           prefetch(c, l + 1);
            else if (c < 7)      prefetch(c + 1, 0);
            // consume own row from LDS, fold sigd4 (uniform -> s_load)
            const float* __restrict__ tr = &tile[buf][t * 68];
            const float* __restrict__ sd = sigd4 + l * 512 + c * 64;
            if (l == 0) {
#pragma unroll
                for (int j = 0; j < 64; j += 4) {
                    const float4 h = *(const float4*)(tr + j);
                    g[j]   = sd[j]   * h.x;
                    g[j+1] = sd[j+1] * h.y;
                    g[j+2] = sd[j+2] * h.z;
                    g[j+3] = sd[j+3] * h.w;
                }
            } else {
#pragma unroll
                for (int j = 0; j < 64; j += 4) {
                    const float4 h = *(const float4*)(tr + j);
                    g[j]   += sd[j]   * h.x;
                    g[j+1] += sd[j+1] * h.y;
                    g[j+2] += sd[j+2] * h.z;
                    g[j+3] += sd[j+3] * h.w;
                }
            }
            buf ^= 1;
        }
        // apply W_read on the l-reduced chunk (uniform -> s_load)
#pragma unroll
        for (int o = 0; o < 8; ++o) {
            const float* __restrict__ wr = W_read + o * 512 + c * 64;
            float p = 0.0f;
#pragma unroll
            for (int j = 0; j < 64; ++j) p += wr[j] * g[j];
            acc[o] += p;
        }
    }

    // ================= epilogue =================
    float4 r0, r1;
    r0.x = acc[0] + out2[0] + b_read[0];
    r0.y = acc[1] + out2[1] + b_read[1];
    r0.z = acc[2] + out2[2] + b_read[2];
    r0.w = acc[3] + out2[3] + b_read[3];
    r1.x = acc[4] + out2[4] + b_read[4];
    r1.y = acc[5] + out2[5] + b_read[5];
    r1.z = acc[6] + out2[6] + b_read[6];
    r1.w = acc[7] + out2[7] + b_read[7];
    *(float4*)(out + (size_t)row * 8)     = r0;
    *(float4*)(out + (size_t)row * 8 + 4) = r1;
}

extern "C" void kernel_launch(void* const* d_in, const int* in_sizes, int n_in,
                              void* d_out, int out_size, void* d_ws, size_t ws_size,
                              hipStream_t stream) {
    (void)n_in; (void)ws_size; (void)out_size;
    const float* x        = (const float*)d_in[0];
    const float* H        = (const float*)d_in[1];
    const float* W_bit    = (const float*)d_in[2];
    const float* b_bit    = (const float*)d_in[3];
    const float* W_bridge = (const float*)d_in[4];
    const float* W_read   = (const float*)d_in[5];
    const float* b_read   = (const float*)d_in[6];
    const float* W_sh     = (const float*)d_in[7];
    const float* b_sh     = (const float*)d_in[8];
    const float* W_eng    = (const float*)d_in[9];
    const float* b_eng    = (const float*)d_in[10];
    const float* W_imp    = (const float*)d_in[11];
    const float* b_imp    = (const float*)d_in[12];
    const float* W_sur    = (const float*)d_in[13];
    const float* b_sur    = (const float*)d_in[14];
    const float* W_gate   = (const float*)d_in[15];
    const float* b_gate   = (const float*)d_in[16];
    const float* decays   = (const float*)d_in[17];
    const float* halt_w   = (const float*)d_in[18];
    const float* halt_b   = (const float*)d_in[19];
    float* out   = (float*)d_out;
    float* sigd4 = (float*)d_ws;                 // 2048 floats = 8 KB

    const int B = in_sizes[1] / 2048;            // H is [B, 4*8*16*4]

    hipLaunchKernelGGL(organism_prep, dim3(8), dim3(256), 0, stream,
                       decays, sigd4);
    hipLaunchKernelGGL(organism_main, dim3(B / 64), dim3(64), 0, stream,
                       x, H, W_bit, b_bit, W_bridge, W_read, b_read,
                       W_sh, b_sh, W_eng, b_eng, W_imp, b_imp,
                       W_sur, b_sur, W_gate, b_gate, halt_w, halt_b,
                       sigd4, out);
}

// Round 3
// 889.072 us; speedup vs baseline: 1.5996x; 1.5996x over previous
//
#include <hip/hip_runtime.h>

__device__ __forceinline__ float sigf(float v) {
    return 1.0f / (1.0f + __expf(-v));
}
__device__ __forceinline__ float tanh_fast(float v) {
    return 1.0f - 2.0f / (__expf(2.0f * v) + 1.0f);
}

// Wave-per-row streaming: each 64-thread block owns 32 rows.
// Phase A (smallnet/term2): lane k computes row r0+(k&31) -> out2 kept in regs.
// Phase B (H contraction/term1): whole wave loads one row per step, fully
// coalesced (lane*16B within 1KB-contiguous chunks). Per-lane rm positions are
// row- and l-invariant, so sigmoid(decays) and W_read slices live in VGPRs.
// Cross-lane reduce via 6-level shfl_xor butterfly; lane rr stores its row.
__global__ __launch_bounds__(64)
void organism_main(const float* __restrict__ x,
                   const float* __restrict__ H,
                   const float* __restrict__ W_bit,
                   const float* __restrict__ b_bit,
                   const float* __restrict__ W_bridge,
                   const float* __restrict__ W_read,
                   const float* __restrict__ b_read,
                   const float* __restrict__ W_sh,
                   const float* __restrict__ b_sh,
                   const float* __restrict__ W_eng,
                   const float* __restrict__ b_eng,
                   const float* __restrict__ W_imp,
                   const float* __restrict__ b_imp,
                   const float* __restrict__ W_sur,
                   const float* __restrict__ b_sur,
                   const float* __restrict__ W_gate,
                   const float* __restrict__ b_gate,
                   const float* __restrict__ decays,
                   const float* __restrict__ halt_w,
                   const float* __restrict__ halt_b,
                   float* __restrict__ out)
{
    const int lane = threadIdx.x;            // 0..63
    const int r0   = blockIdx.x * 32;        // first row owned by this wave
    const int arow = r0 + (lane & 31);       // phase-A row (lanes 32+ duplicate)

    // ---- issue H prefetch for row r0 first (in flight during phase A) ----
    const float* __restrict__ Hl = H + (size_t)r0 * 2048 + lane * 4;
    float4 h[8];
#pragma unroll
    for (int it = 0; it < 8; ++it)
        h[it] = *(const float4*)(Hl + it * 256);

    // ================= phase A: small network (term2 + b_read) ============
    float o2[8];
    {
        float xv[8];
        const float4 x0 = *(const float4*)(x + (size_t)arow * 8);
        const float4 x1 = *(const float4*)(x + (size_t)arow * 8 + 4);
        xv[0]=x0.x; xv[1]=x0.y; xv[2]=x0.z; xv[3]=x0.w;
        xv[4]=x1.x; xv[5]=x1.y; xv[6]=x1.z; xv[7]=x1.w;

        float s1[32];
#pragma unroll
        for (int i = 0; i < 32; ++i) {
            float a = b_bit[i];
#pragma unroll
            for (int k = 0; k < 8; ++k) a += W_bit[i*8+k] * xv[k];
            s1[i] = a;
        }

        float sa = b_sur[0], ga = b_gate[0];
#pragma unroll
        for (int i = 0; i < 32; ++i) {
            sa += W_sur[i]  * s1[i];
            ga += W_gate[i] * s1[i];
        }
        const float sur = sigf(sa) * sigf(ga);

        float s2[64];
#pragma unroll
        for (int m = 0; m < 64; ++m) {
            float a = 0.0f;
#pragma unroll
            for (int i = 0; i < 32; ++i) a += W_bridge[m*32+i] * s1[i];
            s2[m] = tanh_fast(a);
        }

        float ea = b_eng[0], ia = b_imp[0];
        for (int n = 0; n < 64; ++n) {
            float a = b_sh[n];
#pragma unroll
            for (int m = 0; m < 64; ++m) a += W_sh[n*64+m] * s2[m];
            a = fmaxf(a, 0.0f);
            ea += W_eng[n] * a;
            ia += W_imp[n] * a;
        }
        const float ei = sigf(ea) * sigf(ia);

        float wv[64];
#pragma unroll
        for (int m = 0; m < 64; ++m) wv[m] = sur * s2[m];

#pragma unroll
        for (int o = 0; o < 8; ++o) o2[o] = b_read[o];
        for (int r = 0; r < 8; ++r) {
            float hs = 0.0f;
#pragma unroll
            for (int l = 0; l < 4; ++l) {
                float a = halt_b[l];
#pragma unroll
                for (int m = 0; m < 64; ++m) a += halt_w[(l*8+r)*64+m] * s2[m];
                hs += sigf(a);
            }
            const float gr = 0.25f * ei * hs;
#pragma unroll
            for (int o = 0; o < 8; ++o) {
                float p = 0.0f;
#pragma unroll
                for (int m = 0; m < 64; ++m) p += W_read[o*512 + r*64 + m] * wv[m];
                o2[o] += gr * p;
            }
        }
    }

    // ========== per-lane constants (fixed across rows and l) ==============
    // slot s = hf*4+c  <->  rm = hf*256 + lane*4 + c
    float sd[4][8];
#pragma unroll
    for (int l = 0; l < 4; ++l)
#pragma unroll
        for (int hf = 0; hf < 2; ++hf) {
            const float4 d = *(const float4*)(decays + l*512 + hf*256 + lane*4);
            sd[l][hf*4+0] = 0.25f * sigf(d.x);
            sd[l][hf*4+1] = 0.25f * sigf(d.y);
            sd[l][hf*4+2] = 0.25f * sigf(d.z);
            sd[l][hf*4+3] = 0.25f * sigf(d.w);
        }
    float wrv[8][8];
#pragma unroll
    for (int o = 0; o < 8; ++o)
#pragma unroll
        for (int hf = 0; hf < 2; ++hf) {
            const float4 w = *(const float4*)(W_read + o*512 + hf*256 + lane*4);
            wrv[o][hf*4+0] = w.x;
            wrv[o][hf*4+1] = w.y;
            wrv[o][hf*4+2] = w.z;
            wrv[o][hf*4+3] = w.w;
        }

    // ================= phase B: stream 32 rows =============================
#pragma unroll 1
    for (int rr = 0; rr < 32; ++rr) {
        // fold over l: g[slot] = sum_l sd[l][slot] * H[l][rm(slot)]
        float g[8];
#pragma unroll
        for (int hf = 0; hf < 2; ++hf) {
            g[hf*4+0] = sd[0][hf*4+0]*h[hf].x   + sd[1][hf*4+0]*h[2+hf].x
                      + sd[2][hf*4+0]*h[4+hf].x + sd[3][hf*4+0]*h[6+hf].x;
            g[hf*4+1] = sd[0][hf*4+1]*h[hf].y   + sd[1][hf*4+1]*h[2+hf].y
                      + sd[2][hf*4+1]*h[4+hf].y + sd[3][hf*4+1]*h[6+hf].y;
            g[hf*4+2] = sd[0][hf*4+2]*h[hf].z   + sd[1][hf*4+2]*h[2+hf].z
                      + sd[2][hf*4+2]*h[4+hf].z + sd[3][hf*4+2]*h[6+hf].z;
            g[hf*4+3] = sd[0][hf*4+3]*h[hf].w   + sd[1][hf*4+3]*h[2+hf].w
                      + sd[2][hf*4+3]*h[4+hf].w + sd[3][hf*4+3]*h[6+hf].w;
        }

        // prefetch next row's H (h is dead after g); wraps on last iter
        {
            const int nrr = (rr + 1) & 31;
            const float* __restrict__ nb = H + (size_t)(r0 + nrr) * 2048 + lane * 4;
#pragma unroll
            for (int it = 0; it < 8; ++it)
                h[it] = *(const float4*)(nb + it * 256);
        }

        // apply W_read slice
        float acc[8];
#pragma unroll
        for (int o = 0; o < 8; ++o) {
            float a = 0.0f;
#pragma unroll
            for (int s = 0; s < 8; ++s) a += wrv[o][s] * g[s];
            acc[o] = a;
        }

        // 6-level butterfly: every lane ends with the full row sums
#pragma unroll
        for (int m = 1; m <= 32; m <<= 1) {
#pragma unroll
            for (int o = 0; o < 8; ++o)
                acc[o] += __shfl_xor(acc[o], m, 64);
        }

        if (lane == rr) {
            float4 a0, a1;
            a0.x = acc[0] + o2[0]; a0.y = acc[1] + o2[1];
            a0.z = acc[2] + o2[2]; a0.w = acc[3] + o2[3];
            a1.x = acc[4] + o2[4]; a1.y = acc[5] + o2[5];
            a1.z = acc[6] + o2[6]; a1.w = acc[7] + o2[7];
            *(float4*)(out + (size_t)(r0 + rr) * 8)     = a0;
            *(float4*)(out + (size_t)(r0 + rr) * 8 + 4) = a1;
        }
    }
}

extern "C" void kernel_launch(void* const* d_in, const int* in_sizes, int n_in,
                              void* d_out, int out_size, void* d_ws, size_t ws_size,
                              hipStream_t stream) {
    (void)n_in; (void)d_ws; (void)ws_size; (void)out_size;
    const float* x        = (const float*)d_in[0];
    const float* H        = (const float*)d_in[1];
    const float* W_bit    = (const float*)d_in[2];
    const float* b_bit    = (const float*)d_in[3];
    const float* W_bridge = (const float*)d_in[4];
    const float* W_read   = (const float*)d_in[5];
    const float* b_read   = (const float*)d_in[6];
    const float* W_sh     = (const float*)d_in[7];
    const float* b_sh     = (const float*)d_in[8];
    const float* W_eng    = (const float*)d_in[9];
    const float* b_eng    = (const float*)d_in[10];
    const float* W_imp    = (const float*)d_in[11];
    const float* b_imp    = (const float*)d_in[12];
    const float* W_sur    = (const float*)d_in[13];
    const float* b_sur    = (const float*)d_in[14];
    const float* W_gate   = (const float*)d_in[15];
    const float* b_gate   = (const float*)d_in[16];
    const float* decays   = (const float*)d_in[17];
    const float* halt_w   = (const float*)d_in[18];
    const float* halt_b   = (const float*)d_in[19];
    float* out = (float*)d_out;

    const int B = in_sizes[1] / 2048;            // H is [B, 4*8*16*4]
    hipLaunchKernelGGL(organism_main, dim3(B / 32), dim3(64), 0, stream,
                       x, H, W_bit, b_bit, W_bridge, W_read, b_read,
                       W_sh, b_sh, W_eng, b_eng, W_imp, b_imp,
                       W_sur, b_sur, W_gate, b_gate, decays, halt_w, halt_b,
                       out);
}